// Round 6
// baseline (4013.156 us; speedup 1.0000x reference)
//
#include <hip/hip_runtime.h>
#include <hip/hip_bf16.h>
#include <math.h>

#define BB 8
#define LL 64
#define DD 256
#define VV 4096
#define RR 512           // BB*LL
#define K3 768

typedef __attribute__((ext_vector_type(4))) float f32x4;
typedef __attribute__((ext_vector_type(8))) short bf16x8;
typedef __attribute__((ext_vector_type(4))) unsigned short u16x4;
typedef __attribute__((ext_vector_type(8))) unsigned short u16x8;

// ---- workspace layout (float offsets) -----------------------------------
#define WS_ZE      0
#define WS_ZEU3    (WS_ZE + RR*DD)           // dead after scan
#define WS_WCT     (WS_ZEU3 + RR*DD)         // dead after scan
#define WS_XSA0    (WS_WCT + DD*K3)          // dead after k_sel
#define WS_XSA1    (WS_XSA0 + RR*DD)         // dead after scan
#define WS_EMIT    (WS_XSA1 + RR*DD)
#define WS_YVEC    (WS_EMIT + RR*DD)
#define WS_X0VEC   (WS_YVEC + DD)
#define WS_YK      (WS_X0VEC + DD)
#define WS_YLOG    (WS_YK + DD)
#define WS_YLSE    (WS_YLOG + VV)
#define WS_SEL     (WS_YLSE + 8)
#define WS_LSE     (WS_SEL + RR*4)
#define WS_TGT     (WS_LSE + 1024)
#define WS_CNT     (WS_TGT + 1024)           // 64 ints, ends 861000 < 861184
// Overlays (regions dead after the scan):
#define WS_HPART   WS_WCT                    // 1024*64*2 = 131072 <= 196608
#define WS_UHI     WS_ZEU3
#define WS_ULO     WS_XSA1
// MFMA-only tail:
#define WS_EHI     861184
#define WS_ELO     (WS_EHI + VV*DD/2)
#define WS_TOTAL_MFMA (WS_ELO + VV*DD/2)     // 7,639,040 bytes

__device__ __forceinline__ float waveSum(float v) {
#pragma unroll
  for (int o = 32; o > 0; o >>= 1) v += __shfl_xor(v, o, 64);
  return v;
}

__device__ __forceinline__ float blockSum256(float v) {
  __shared__ float red[4];
  int lane = threadIdx.x & 63, w = threadIdx.x >> 6;
  v = waveSum(v);
  __syncthreads();
  if (lane == 0) red[w] = v;
  __syncthreads();
  return red[0] + red[1] + red[2] + red[3];
}

__device__ __forceinline__ unsigned short f2bf(float f) {
  unsigned int u = __float_as_uint(f);
  unsigned int r = (u + 0x7fffu + ((u >> 16) & 1u)) >> 16;
  return (unsigned short)r;
}
__device__ __forceinline__ float bf2f(unsigned short h) {
  return __uint_as_float(((unsigned int)h) << 16);
}

// --- normalize rows: ze (512), yvec, x0vec -------------------------------
__global__ __launch_bounds__(256) void k_norm_rows(
    const int* __restrict__ z, const float* __restrict__ embed,
    const float* __restrict__ initw, float* __restrict__ ws) {
  int r = blockIdx.x, d = threadIdx.x;
  float a; float* dst;
  if (r < RR) { int tok = z[r]; a = embed[tok * DD + d]; dst = ws + WS_ZE + r * DD; }
  else if (r == RR) { a = embed[d]; dst = ws + WS_YVEC; }
  else { a = initw[d * 16]; dst = ws + WS_X0VEC; }
  float s  = blockSum256(a);
  float sq = blockSum256(a * a);
  float mean = s * (1.0f / DD);
  float var = fmaxf((sq - (float)DD * mean * mean) * (1.0f / (DD - 1)), 0.0f);
  dst[d] = a / (1e-5f + sqrtf(var));
}

// --- build combined transposed weights WcT[c][0:768] = [Tw;TwT;Cw]/3 -----
__global__ __launch_bounds__(256) void k_build_w(
    const float* __restrict__ tw, const float* __restrict__ cw,
    float* __restrict__ wct) {
  int c = blockIdx.x, k = threadIdx.x;
  const float inv3 = 1.0f / 3.0f;
  wct[c * K3 + k]       = tw[k * DD + c] * inv3;  // x[l-1] @ Tw
  wct[c * K3 + 256 + k] = tw[c * DD + k] * inv3;  // x[l+1] @ Tw^T
  wct[c * K3 + 512 + k] = cw[k * DD + c] * inv3;  // x[l]   @ Cw
}

// --- yk = yvec @ xkd_w^T + xkd_b -----------------------------------------
__global__ __launch_bounds__(256) void k_yk(
    const float* __restrict__ xkdw, const float* __restrict__ xkdb,
    float* __restrict__ ws) {
  int d = threadIdx.x;
  __shared__ float y[DD];
  y[d] = ws[WS_YVEC + d];
  __syncthreads();
  float acc = xkdb[d];
  for (int k = 0; k < DD; k++) acc += y[k] * xkdw[d * DD + k];
  ws[WS_YK + d] = acc;
}

// --- broadcast x0vec into xsa buffer 0 -----------------------------------
__global__ __launch_bounds__(256) void k_bcast(float* __restrict__ ws) {
  int r = blockIdx.x, d = threadIdx.x;
  ws[WS_XSA0 + r * DD + d] = ws[WS_X0VEC + d];
}

// --- out[r][d] = scale*(in[r]·W[d,:] + bias[d]) ; 2 rows / block ----------
__global__ __launch_bounds__(256) void k_rowmat2(
    const float* __restrict__ in, const float* __restrict__ W,
    const float* __restrict__ bias, float* __restrict__ out, float scale) {
  int r0 = blockIdx.x * 2, d = threadIdx.x;
  __shared__ float u[2][260];
  u[0][d] = in[r0 * DD + d];
  u[1][d] = in[(r0 + 1) * DD + d];
  __syncthreads();
  float a0 = 0.f, a1 = 0.f;
  const float4* w4 = (const float4*)(W + d * DD);
  const float4* u0 = (const float4*)&u[0][0];
  const float4* u1 = (const float4*)&u[1][0];
#pragma unroll 8
  for (int k4 = 0; k4 < 64; k4++) {
    float4 w = w4[k4], x0 = u0[k4], x1 = u1[k4];
    a0 += x0.x*w.x + x0.y*w.y + x0.z*w.z + x0.w*w.w;
    a1 += x1.x*w.x + x1.y*w.y + x1.z*w.z + x1.w*w.w;
  }
  float b = bias[d];
  out[r0 * DD + d]       = (a0 + b) * scale;
  out[(r0 + 1) * DD + d] = (a1 + b) * scale;
}

// --- zero the 64 rowgroup counters (each graph replay) -------------------
__global__ void k_zero_cnt(int* __restrict__ c) { c[threadIdx.x] = 0; }

// --- persistent cooperative scan: all 64 steps in one kernel -------------
// 512 blocks (2/CU), 256 thr. Block = 8 rows x 32 cols. W in VGPRs (once).
// Thread (cl in 0..7 -> 4 cols, rs in 0..31 -> 8-k window per part).
// Neighbor sync via per-(batch,rowgroup) monotonic counters.
__global__ __launch_bounds__(256, 2) void k_scan(float* __restrict__ ws) {
  const int bid = blockIdx.x;
  // swizzle: siblings (same rowgroup, all 8 cg) land on one XCD (bid%8 equal)
  const int rg = bid & 63, cg = bid >> 6;
  const int b = rg >> 3, rgl = rg & 7, l0 = rgl * 8;
  const int t = threadIdx.x;
  const int cl = t & 7, rs = t >> 3;
  const int c0 = cg * 32 + cl * 4;

  __shared__ float S[10 * 264];     // staged x rows l0-1..l0+8
  __shared__ float PAR[32 * 260];   // split-K partials
  __shared__ float PAR2[4 * 256];
  __shared__ float ZB[256];         // zeu3 tile (step-invariant)

  const float* wct  = ws + WS_WCT;
  const float* zeu3 = ws + WS_ZEU3;
  int* cnt = (int*)(ws + WS_CNT);

  // ---- W into registers: 4 cols x 3 parts x 8 k = 96 floats (24 float4)
  float4 wreg[24];
#pragma unroll
  for (int p = 0; p < 3; ++p)
#pragma unroll
    for (int q = 0; q < 2; ++q)
#pragma unroll
      for (int c4 = 0; c4 < 4; ++c4)
        wreg[(p * 2 + q) * 4 + c4] =
            *(const float4*)&wct[(size_t)(c0 + c4) * K3 + p * 256 + rs * 8 + q * 4];

  { // zeu3 tile
    int r = t >> 5, c = t & 31;
    ZB[r * 32 + c] = zeu3[(size_t)(b * 64 + l0 + r) * DD + cg * 32 + c];
  }

  const int cw0 = b * 8 + ((rgl + 7) & 7);
  const int cw1 = b * 8 + rgl;
  const int cw2 = b * 8 + ((rgl + 1) & 7);

  for (int st = 0; st < 64; ++st) {
    const float* xin = ws + ((st & 1) ? WS_XSA1 : WS_XSA0);
    float*       xout = ws + ((st & 1) ? WS_XSA0 : WS_XSA1);

    if (st > 0) {
      if (t == 0) {
        const int tg = 8 * st;
        while (__hip_atomic_load(&cnt[cw0], __ATOMIC_ACQUIRE, __HIP_MEMORY_SCOPE_AGENT) < tg ||
               __hip_atomic_load(&cnt[cw1], __ATOMIC_ACQUIRE, __HIP_MEMORY_SCOPE_AGENT) < tg ||
               __hip_atomic_load(&cnt[cw2], __ATOMIC_ACQUIRE, __HIP_MEMORY_SCOPE_AGENT) < tg) {
          __builtin_amdgcn_s_sleep(1);
        }
      }
      __syncthreads();
    }

    // stage 10 rows x 256 f (vectorized, coalesced)
#pragma unroll
    for (int it = 0; it < 3; ++it) {
      int idx = it * 256 + t;
      if (idx < 640) {
        int j = idx >> 6, kk = (idx & 63) * 4;
        int l = (l0 + j - 1 + 64) & 63;
        *(float4*)&S[j * 264 + kk] =
            *(const float4*)&xin[(size_t)(b * 64 + l) * DD + kk];
      }
    }
    __syncthreads();

    float acc[8][4];
#pragma unroll
    for (int r = 0; r < 8; ++r)
#pragma unroll
      for (int c4 = 0; c4 < 4; ++c4) acc[r][c4] = 0.f;

#pragma unroll
    for (int p = 0; p < 3; ++p) {
      const int jof = (p == 0) ? 0 : (p == 1) ? 2 : 1;
#pragma unroll
      for (int r = 0; r < 8; ++r) {
#pragma unroll
        for (int q = 0; q < 2; ++q) {
          float4 x = *(const float4*)&S[(r + jof) * 264 + rs * 8 + q * 4];
#pragma unroll
          for (int c4 = 0; c4 < 4; ++c4) {
            float4 w = wreg[(p * 2 + q) * 4 + c4];
            acc[r][c4] += x.x * w.x + x.y * w.y + x.z * w.z + x.w * w.w;
          }
        }
      }
    }

    // partials -> LDS
#pragma unroll
    for (int r = 0; r < 8; ++r) {
      float4 v4 = {acc[r][0], acc[r][1], acc[r][2], acc[r][3]};
      *(float4*)&PAR[rs * 260 + r * 32 + cl * 4] = v4;
    }
    __syncthreads();

    { // reduce 32 -> 4
      int u = t & 63, v = t >> 6;
      int r = u >> 3, c8 = u & 7;
      float4 s4 = {0.f, 0.f, 0.f, 0.f};
#pragma unroll
      for (int i = 0; i < 8; ++i) {
        float4 p4 = *(const float4*)&PAR[(v * 8 + i) * 260 + r * 32 + c8 * 4];
        s4.x += p4.x; s4.y += p4.y; s4.z += p4.z; s4.w += p4.w;
      }
      *(float4*)&PAR2[v * 256 + u * 4] = s4;
    }
    __syncthreads();

    if (t < 64) { // reduce 4 -> 1, add zeu3, write out
      int r = t >> 3, c8 = t & 7;
      float4 s4 = {0.f, 0.f, 0.f, 0.f};
#pragma unroll
      for (int v = 0; v < 4; ++v) {
        float4 p4 = *(const float4*)&PAR2[v * 256 + t * 4];
        s4.x += p4.x; s4.y += p4.y; s4.z += p4.z; s4.w += p4.w;
      }
      float4 zb = *(const float4*)&ZB[r * 32 + c8 * 4];
      s4.x += zb.x; s4.y += zb.y; s4.z += zb.z; s4.w += zb.w;
      *(float4*)&xout[(size_t)(b * 64 + l0 + r) * DD + cg * 32 + c8 * 4] = s4;
    }

    __threadfence();
    __syncthreads();
    if (t == 0)
      __hip_atomic_fetch_add(&cnt[cw1], 1, __ATOMIC_RELEASE, __HIP_MEMORY_SCOPE_AGENT);
  }
}

// --- fallback single step (used only if cooperative launch fails) --------
__global__ __launch_bounds__(256) void k_step(
    const float* __restrict__ xin, const float* __restrict__ wct,
    const float* __restrict__ zeu3, float* __restrict__ xout) {
  int rg = blockIdx.x, cg = blockIdx.y;
  int b = rg >> 3, l0 = (rg & 7) * 8;
  int t = threadIdx.x, cl = t & 31, rs = t >> 5;
  int c = cg * 32 + cl;
  __shared__ float S[10][256];
  const float* xb = xin + b * LL * DD;
#pragma unroll
  for (int j = 0; j < 10; ++j) {
    int l = (l0 + j - 1 + LL) & (LL - 1);
    S[j][t] = xb[l * DD + t];
  }
  __syncthreads();
  float a0 = 0.f;
  const float* wb = wct + c * K3;
#pragma unroll
  for (int p = 0; p < 3; ++p) {
    int j0 = rs + ((p == 0) ? 0 : (p == 1) ? 2 : 1);
    const float4* w4 = (const float4*)(wb + p * 256);
    const float4* u0 = (const float4*)&S[j0][0];
#pragma unroll 16
    for (int k4 = 0; k4 < 64; ++k4) {
      float4 w = w4[k4], x0 = u0[k4];
      a0 += x0.x*w.x + x0.y*w.y + x0.z*w.z + x0.w*w.w;
    }
  }
  int r0 = b * LL + l0 + rs;
  xout[r0 * DD + c] = a0 + zeu3[r0 * DD + c];
}

// --- split embed into bf16 hi/lo (MFMA path only) ------------------------
__global__ __launch_bounds__(256) void k_split_e(
    const float* __restrict__ e, unsigned short* __restrict__ eh,
    unsigned short* __restrict__ el) {
  int i = (blockIdx.x * 256 + threadIdx.x) * 4;
  float4 v = *(const float4*)(e + i);
  float f[4] = {v.x, v.y, v.z, v.w};
  u16x4 h, l;
#pragma unroll
  for (int j = 0; j < 4; ++j) {
    unsigned short hb = f2bf(f[j]);
    h[j] = hb;
    l[j] = f2bf(f[j] - bf2f(hb));
  }
  *(u16x4*)(eh + i) = h;
  *(u16x4*)(el + i) = l;
}

// --- split U = [emit ; ze] into bf16 hi/lo (MFMA path only) --------------
__global__ __launch_bounds__(256) void k_split_u(float* __restrict__ ws) {
  int row = blockIdx.x, d = threadIdx.x;
  float v = (row < RR) ? ws[WS_EMIT + row * DD + d]
                       : ws[WS_ZE + (row - RR) * DD + d];
  unsigned short hb = f2bf(v);
  unsigned short lb = f2bf(v - bf2f(hb));
  ((unsigned short*)(ws + WS_UHI))[row * DD + d] = hb;
  ((unsigned short*)(ws + WS_ULO))[row * DD + d] = lb;
}

// --- head GEMM via MFMA, split-precision bf16, fused online LSE ----------
// grid (32 rowgroups of 32, 32 vchunks of 128), 256 thr = 4 waves.
// wave (wr=w>>1, wc=w&1): rows [row0+wr*16,+16) x v [v0+wc*64,+64).
__global__ __launch_bounds__(256) void k_head_mfma(
    const unsigned short* __restrict__ uh, const unsigned short* __restrict__ ul,
    const unsigned short* __restrict__ eh, const unsigned short* __restrict__ el,
    float* __restrict__ hpart) {
  int row0 = blockIdx.x * 32;
  int v0 = blockIdx.y * 128;
  int t = threadIdx.x, lane = t & 63, w = t >> 6;
  int wr = w >> 1, wc = w & 1;
  __shared__ unsigned short UH[32 * 264];
  __shared__ unsigned short UL[32 * 264];
#pragma unroll
  for (int it = 0; it < 4; ++it) {
    int r = it * 8 + (t >> 5);
    int c8 = (t & 31) * 8;
    *(u16x8*)(&UH[r * 264 + c8]) = *(const u16x8*)(uh + (row0 + r) * DD + c8);
    *(u16x8*)(&UL[r * 264 + c8]) = *(const u16x8*)(ul + (row0 + r) * DD + c8);
  }
  __syncthreads();

  f32x4 acc[4];
#pragma unroll
  for (int q = 0; q < 4; ++q) acc[q] = (f32x4){0.f, 0.f, 0.f, 0.f};

  int arow = wr * 16 + (lane & 15);
  int kof = 8 * (lane >> 4);
  const unsigned short* Ah = &UH[arow * 264 + kof];
  const unsigned short* Al = &UL[arow * 264 + kof];
  int vbase = v0 + wc * 64 + (lane & 15);

#pragma unroll
  for (int p = 0; p < 3; ++p) {
    const unsigned short* Ab = (p == 2) ? Al : Ah;
    const unsigned short* Ebl = ((p == 1) ? el : eh) + (size_t)vbase * DD + kof;
#pragma unroll
    for (int ks = 0; ks < 8; ++ks) {
      int k0 = ks * 32;
      bf16x8 a = *(const bf16x8*)(Ab + k0);
#pragma unroll
      for (int vt = 0; vt < 4; ++vt) {
        bf16x8 bfr = *(const bf16x8*)(Ebl + vt * 16 * DD + k0);
        acc[vt] = __builtin_amdgcn_mfma_f32_16x16x32_bf16(a, bfr, acc[vt], 0, 0, 0);
      }
    }
  }

  int chunk = blockIdx.y * 2 + wc;   // 0..63
#pragma unroll
  for (int i = 0; i < 4; ++i) {
    float mm = -1e30f;
#pragma unroll
    for (int vt = 0; vt < 4; ++vt) mm = fmaxf(mm, acc[vt][i]);
#pragma unroll
    for (int o = 1; o < 16; o <<= 1) mm = fmaxf(mm, __shfl_xor(mm, o, 64));
    float ss = 0.f;
#pragma unroll
    for (int vt = 0; vt < 4; ++vt) ss += __expf(acc[vt][i] - mm);
#pragma unroll
    for (int o = 1; o < 16; o <<= 1) ss += __shfl_xor(ss, o, 64);
    if ((lane & 15) == 0) {
      int row = row0 + wr * 16 + (lane >> 4) * 4 + i;
      hpart[(row * 64 + chunk) * 2]     = mm;
      hpart[(row * 64 + chunk) * 2 + 1] = ss;
    }
  }
}

// --- fallback f32 head: grid (64 rowgroups of 16, 32 vchunks of 128) -----
__global__ __launch_bounds__(256) void k_head_f32(
    const float* __restrict__ embed, float* __restrict__ ws) {
  int rg = blockIdx.x, vc = blockIdx.y;
  int t = threadIdx.x, vl = t & 63, rs = t >> 6;
  __shared__ float U[16][260];
  int row0 = rg * 16;
  const float* src = (row0 < RR) ? (ws + WS_EMIT + row0 * DD)
                                 : (ws + WS_ZE + (row0 - RR) * DD);
  for (int j = 0; j < 16; j++) U[j][t] = src[j * DD + t];
  __syncthreads();
  float m[4], s[4];
#pragma unroll
  for (int q = 0; q < 4; q++) { m[q] = -1e30f; s[q] = 0.f; }
  for (int it = 0; it < 2; it++) {
    int v = vc * 128 + it * 64 + vl;
    const float4* e4 = (const float4*)(embed + (size_t)v * DD);
    float acc[4] = {0.f, 0.f, 0.f, 0.f};
#pragma unroll 4
    for (int k4 = 0; k4 < 64; k4++) {
      float4 e = e4[k4];
#pragma unroll
      for (int q = 0; q < 4; q++) {
        float4 u = ((const float4*)&U[rs + q*4][0])[k4];
        acc[q] += u.x*e.x + u.y*e.y + u.z*e.z + u.w*e.w;
      }
    }
#pragma unroll
    for (int q = 0; q < 4; q++) {
      float mn = fmaxf(m[q], acc[q]);
      s[q] = s[q] * __expf(m[q] - mn) + __expf(acc[q] - mn);
      m[q] = mn;
    }
  }
#pragma unroll
  for (int o = 32; o > 0; o >>= 1) {
#pragma unroll
    for (int q = 0; q < 4; q++) {
      float mo = __shfl_xor(m[q], o, 64), so = __shfl_xor(s[q], o, 64);
      float mn = fmaxf(m[q], mo);
      s[q] = s[q] * __expf(m[q] - mn) + so * __expf(mo - mn);
      m[q] = mn;
    }
  }
  if (vl == 0) {
#pragma unroll
    for (int q = 0; q < 4; q++) {
      int row = row0 + rs + q*4;
      ws[WS_HPART + (row*32 + vc)*2]     = m[q];
      ws[WS_HPART + (row*32 + vc)*2 + 1] = s[q];
    }
  }
}

// --- ylog[v] = yvec · embed[v] -------------------------------------------
__global__ __launch_bounds__(256) void k_ylog(
    const float* __restrict__ embed, float* __restrict__ ws) {
  __shared__ float y[DD];
  int t = threadIdx.x;
  y[t] = ws[WS_YVEC + t];
  __syncthreads();
  int w = t >> 6, lane = t & 63;
  for (int i = 0; i < 16; i++) {
    int v = blockIdx.x * 64 + i * 4 + w;
    float p = 0.f;
#pragma unroll
    for (int j = 0; j < 4; j++) p += y[lane + 64*j] * embed[v * DD + lane + 64*j];
    p = waveSum(p);
    if (lane == 0) ws[WS_YLOG + v] = p;
  }
}

// --- ylse = logsumexp(ylog) ----------------------------------------------
__global__ __launch_bounds__(256) void k_ylse(float* __restrict__ ws) {
  int t = threadIdx.x;
  float m = -1e30f, s = 0.f;
  for (int v = t; v < VV; v += 256) {
    float lg = ws[WS_YLOG + v];
    float mn = fmaxf(m, lg);
    s = s * __expf(m - mn) + __expf(lg - mn);
    m = mn;
  }
#pragma unroll
  for (int o = 32; o > 0; o >>= 1) {
    float mo = __shfl_xor(m, o, 64), so = __shfl_xor(s, o, 64);
    float mn = fmaxf(m, mo);
    s = s * __expf(m - mn) + so * __expf(mo - mn);
    m = mn;
  }
  __shared__ float rm[4], rv[4];
  int lane = t & 63, w = t >> 6;
  if (lane == 0) { rm[w] = m; rv[w] = s; }
  __syncthreads();
  if (t == 0) {
    float M = fmaxf(fmaxf(rm[0], rm[1]), fmaxf(rm[2], rm[3]));
    float S = rv[0]*__expf(rm[0]-M) + rv[1]*__expf(rm[1]-M) +
              rv[2]*__expf(rm[2]-M) + rv[3]*__expf(rm[3]-M);
    ws[WS_YLSE] = M + logf(S);
  }
}

// --- sel logits: s0,s1,s2 per row ----------------------------------------
__global__ __launch_bounds__(256) void k_sel(
    const float* __restrict__ xks, float* __restrict__ ws) {
  int row = blockIdx.x * 4 + (threadIdx.x >> 6);
  int lane = threadIdx.x & 63;
  const float* xr = ws + WS_XSA0 + row * DD;
  float a0 = 0.f, a1 = 0.f, a2 = 0.f;
#pragma unroll
  for (int j = 0; j < 4; j++) {
    float xv = xr[lane + 64*j];
    a0 += xv * xks[lane + 64*j];
    a1 += xv * xks[DD + lane + 64*j];
    a2 += xv * ws[WS_YK + lane + 64*j];
  }
  a0 = waveSum(a0); a1 = waveSum(a1); a2 = waveSum(a2);
  if (lane == 0) {
    ws[WS_SEL + row*4 + 0] = a0;
    ws[WS_SEL + row*4 + 1] = a1;
    ws[WS_SEL + row*4 + 2] = a2;
  }
}

// --- target logits: dot(cand_row, embed[x]) ------------------------------
__global__ __launch_bounds__(256) void k_tgt(
    const int* __restrict__ x, const float* __restrict__ embed,
    float* __restrict__ ws) {
  int row = blockIdx.x * 4 + (threadIdx.x >> 6);
  int lane = threadIdx.x & 63;
  int r5 = row & (RR - 1);
  const float* vec = (row < RR) ? (ws + WS_EMIT + r5 * DD) : (ws + WS_ZE + r5 * DD);
  int v = x[r5];
  float p = 0.f;
#pragma unroll
  for (int j = 0; j < 4; j++) p += vec[lane + 64*j] * embed[v * DD + lane + 64*j];
  p = waveSum(p);
  if (lane == 0) ws[WS_TGT + row] = p;
}

// --- combine nch per-chunk partials into per-row LSE ---------------------
__global__ __launch_bounds__(256) void k_comb(float* __restrict__ ws, int nch) {
  int row = blockIdx.x * 256 + threadIdx.x;
  const float* hp = ws + WS_HPART + row * nch * 2;
  float M = -1e30f;
  for (int c = 0; c < nch; c++) M = fmaxf(M, hp[c * 2]);
  float S = 0.f;
  for (int c = 0; c < nch; c++) S += hp[c * 2 + 1] * __expf(hp[c * 2] - M);
  ws[WS_LSE + row] = M + logf(S);
}

// --- final: mixture prob at target, sqrt, mean over L, negate ------------
__global__ __launch_bounds__(64) void k_final(
    const int* __restrict__ x, float* __restrict__ ws, float* __restrict__ out) {
  int b = blockIdx.x, l = threadIdx.x, r = b * 64 + l;
  float s0 = ws[WS_SEL + r*4], s1 = ws[WS_SEL + r*4+1], s2 = ws[WS_SEL + r*4+2];
  float mx = fmaxf(s0, fmaxf(s1, s2));
  float den = expf(s0 - mx) + expf(s1 - mx) + 64.f * expf(s2 - mx);
  float lsel = mx + logf(den);
  int xv = x[r];
  float P0 = expf(s0 - lsel + ws[WS_TGT + r]      - ws[WS_LSE + r]);
  float P1 = expf(s1 - lsel + ws[WS_TGT + RR + r] - ws[WS_LSE + RR + r]);
  float Py = expf(s2 - lsel + ws[WS_YLOG + xv]    - ws[WS_YLSE]);
  float cent = sqrtf(P0 + P1 + 64.f * Py);
  float sum = waveSum(cent);
  if (l == 0) out[b] = -(sum * (1.0f / 64.f));
}

extern "C" void kernel_launch(void* const* d_in, const int* in_sizes, int n_in,
                              void* d_out, int out_size, void* d_ws, size_t ws_size,
                              hipStream_t stream) {
  (void)in_sizes; (void)n_in; (void)out_size;
  const int*   x     = (const int*)d_in[0];
  const int*   z     = (const int*)d_in[1];
  const float* embed = (const float*)d_in[2];
  const float* initw = (const float*)d_in[3];
  const float* tw    = (const float*)d_in[4];
  const float* tb    = (const float*)d_in[5];
  const float* cw    = (const float*)d_in[6];
  const float* uw    = (const float*)d_in[7];
  const float* xks   = (const float*)d_in[8];
  const float* xkdw  = (const float*)d_in[9];
  const float* xkdb  = (const float*)d_in[10];
  const float* emiw  = (const float*)d_in[11];
  const float* emib  = (const float*)d_in[12];
  float* ws  = (float*)d_ws;
  float* out = (float*)d_out;

  const bool use_mfma = ws_size >= (size_t)WS_TOTAL_MFMA * sizeof(float);

  hipLaunchKernelGGL(k_norm_rows, dim3(RR + 2), dim3(256), 0, stream, z, embed, initw, ws);
  hipLaunchKernelGGL(k_build_w,   dim3(256),    dim3(256), 0, stream, tw, cw, ws + WS_WCT);
  hipLaunchKernelGGL(k_yk,        dim3(1),      dim3(256), 0, stream, xkdw, xkdb, ws);
  hipLaunchKernelGGL(k_bcast,     dim3(512),    dim3(256), 0, stream, ws);
  hipLaunchKernelGGL(k_rowmat2,   dim3(256),    dim3(256), 0, stream,
                     ws + WS_ZE, uw, tb, ws + WS_ZEU3, 1.0f / 3.0f);
  if (use_mfma) {
    hipLaunchKernelGGL(k_split_e, dim3(1024),   dim3(256), 0, stream, embed,
                       (unsigned short*)(ws + WS_EHI), (unsigned short*)(ws + WS_ELO));
  }
  hipLaunchKernelGGL(k_ylog,      dim3(64),     dim3(256), 0, stream, embed, ws);
  hipLaunchKernelGGL(k_ylse,      dim3(1),      dim3(256), 0, stream, ws);

  // ---- scan: persistent cooperative kernel (fallback: 64 step launches) --
  hipLaunchKernelGGL(k_zero_cnt, dim3(1), dim3(64), 0, stream, (int*)(ws + WS_CNT));
  {
    float* wsp = ws;
    void* kargs[] = {&wsp};
    hipError_t err = hipLaunchCooperativeKernel(
        reinterpret_cast<void*>(k_scan), dim3(512), dim3(256), kargs, 0, stream);
    if (err != hipSuccess) {
      for (int t = 0; t < 64; t++) {
        const float* xin = ws + ((t & 1) ? WS_XSA1 : WS_XSA0);
        float*       xo  = ws + ((t & 1) ? WS_XSA0 : WS_XSA1);
        hipLaunchKernelGGL(k_step, dim3(64, 8), dim3(256), 0, stream,
                           xin, ws + WS_WCT, ws + WS_ZEU3, xo);
      }
    }
  }

  hipLaunchKernelGGL(k_rowmat2, dim3(256), dim3(256), 0, stream,
                     ws + WS_XSA0, emiw, emib, ws + WS_EMIT, 1.0f);
  hipLaunchKernelGGL(k_sel,     dim3(128), dim3(256), 0, stream, xks, ws);
  hipLaunchKernelGGL(k_tgt,     dim3(256), dim3(256), 0, stream, x, embed, ws);
  if (use_mfma) {
    hipLaunchKernelGGL(k_split_u,   dim3(1024),   dim3(256), 0, stream, ws);
    hipLaunchKernelGGL(k_head_mfma, dim3(32, 32), dim3(256), 0, stream,
                       (const unsigned short*)(ws + WS_UHI),
                       (const unsigned short*)(ws + WS_ULO),
                       (const unsigned short*)(ws + WS_EHI),
                       (const unsigned short*)(ws + WS_ELO),
                       ws + WS_HPART);
    hipLaunchKernelGGL(k_comb,  dim3(4), dim3(256), 0, stream, ws, 64);
  } else {
    hipLaunchKernelGGL(k_head_f32, dim3(64, 32), dim3(256), 0, stream, embed, ws);
    hipLaunchKernelGGL(k_comb,  dim3(4), dim3(256), 0, stream, ws, 32);
  }
  hipLaunchKernelGGL(k_final, dim3(8), dim3(64),  0, stream, x, ws, out);
}

// Round 7
// 799.813 us; speedup vs baseline: 5.0176x; 5.0176x over previous
//
#include <hip/hip_runtime.h>
#include <hip/hip_bf16.h>
#include <math.h>

#define BB 8
#define LL 64
#define DD 256
#define VV 4096
#define RR 512           // BB*LL
#define K3 768

typedef __attribute__((ext_vector_type(4))) float f32x4;
typedef __attribute__((ext_vector_type(8))) short bf16x8;
typedef __attribute__((ext_vector_type(4))) unsigned short u16x4;
typedef __attribute__((ext_vector_type(8))) unsigned short u16x8;
typedef unsigned long long u64;

// ---- workspace layout (float offsets) -----------------------------------
#define WS_ZE      0
#define WS_ZEU3    (WS_ZE + RR*DD)           // dead after scan
#define WS_WCT     (WS_ZEU3 + RR*DD)         // dead after scan
#define WS_XSA0    (WS_WCT + DD*K3)          // dead after k_sel
#define WS_XSA1    (WS_XSA0 + RR*DD)         // dead after scan
#define WS_EMIT    (WS_XSA1 + RR*DD)
#define WS_YVEC    (WS_EMIT + RR*DD)
#define WS_X0VEC   (WS_YVEC + DD)
#define WS_YK      (WS_X0VEC + DD)
#define WS_YLOG    (WS_YK + DD)
#define WS_YLSE    (WS_YLOG + VV)
#define WS_SEL     (WS_YLSE + 8)
#define WS_LSE     (WS_SEL + RR*4)
#define WS_TGT     (WS_LSE + 1024)
#define WS_CNT     (WS_TGT + 1024)           // 64 ints
// Overlays (regions dead after the scan):
#define WS_HPART   WS_WCT                    // 1024*64*2 = 131072 <= 196608
#define WS_UHI     WS_ZEU3
#define WS_ULO     WS_XSA1
// MFMA-only tail:
#define WS_EHI     861184
#define WS_ELO     (WS_EHI + VV*DD/2)
#define WS_TOTAL_MFMA (WS_ELO + VV*DD/2)     // 7,639,040 bytes

__device__ __forceinline__ float waveSum(float v) {
#pragma unroll
  for (int o = 32; o > 0; o >>= 1) v += __shfl_xor(v, o, 64);
  return v;
}

__device__ __forceinline__ float blockSum256(float v) {
  __shared__ float red[4];
  int lane = threadIdx.x & 63, w = threadIdx.x >> 6;
  v = waveSum(v);
  __syncthreads();
  if (lane == 0) red[w] = v;
  __syncthreads();
  return red[0] + red[1] + red[2] + red[3];
}

__device__ __forceinline__ unsigned short f2bf(float f) {
  unsigned int u = __float_as_uint(f);
  unsigned int r = (u + 0x7fffu + ((u >> 16) & 1u)) >> 16;
  return (unsigned short)r;
}
__device__ __forceinline__ float bf2f(unsigned short h) {
  return __uint_as_float(((unsigned int)h) << 16);
}

union U64F2 { u64 u; float f[2]; };

// --- normalize rows: ze (512), yvec, x0vec -------------------------------
__global__ __launch_bounds__(256) void k_norm_rows(
    const int* __restrict__ z, const float* __restrict__ embed,
    const float* __restrict__ initw, float* __restrict__ ws) {
  int r = blockIdx.x, d = threadIdx.x;
  float a; float* dst;
  if (r < RR) { int tok = z[r]; a = embed[tok * DD + d]; dst = ws + WS_ZE + r * DD; }
  else if (r == RR) { a = embed[d]; dst = ws + WS_YVEC; }
  else { a = initw[d * 16]; dst = ws + WS_X0VEC; }
  float s  = blockSum256(a);
  float sq = blockSum256(a * a);
  float mean = s * (1.0f / DD);
  float var = fmaxf((sq - (float)DD * mean * mean) * (1.0f / (DD - 1)), 0.0f);
  dst[d] = a / (1e-5f + sqrtf(var));
}

// --- build combined transposed weights WcT[c][0:768] = [Tw;TwT;Cw]/3 -----
__global__ __launch_bounds__(256) void k_build_w(
    const float* __restrict__ tw, const float* __restrict__ cw,
    float* __restrict__ wct) {
  int c = blockIdx.x, k = threadIdx.x;
  const float inv3 = 1.0f / 3.0f;
  wct[c * K3 + k]       = tw[k * DD + c] * inv3;  // x[l-1] @ Tw
  wct[c * K3 + 256 + k] = tw[c * DD + k] * inv3;  // x[l+1] @ Tw^T
  wct[c * K3 + 512 + k] = cw[k * DD + c] * inv3;  // x[l]   @ Cw
}

// --- yk = yvec @ xkd_w^T + xkd_b -----------------------------------------
__global__ __launch_bounds__(256) void k_yk(
    const float* __restrict__ xkdw, const float* __restrict__ xkdb,
    float* __restrict__ ws) {
  int d = threadIdx.x;
  __shared__ float y[DD];
  y[d] = ws[WS_YVEC + d];
  __syncthreads();
  float acc = xkdb[d];
  for (int k = 0; k < DD; k++) acc += y[k] * xkdw[d * DD + k];
  ws[WS_YK + d] = acc;
}

// --- broadcast x0vec into xsa buffer 0 -----------------------------------
__global__ __launch_bounds__(256) void k_bcast(float* __restrict__ ws) {
  int r = blockIdx.x, d = threadIdx.x;
  ws[WS_XSA0 + r * DD + d] = ws[WS_X0VEC + d];
}

// --- out[r][d] = scale*(in[r]·W[d,:] + bias[d]) ; 2 rows / block ----------
__global__ __launch_bounds__(256) void k_rowmat2(
    const float* __restrict__ in, const float* __restrict__ W,
    const float* __restrict__ bias, float* __restrict__ out, float scale) {
  int r0 = blockIdx.x * 2, d = threadIdx.x;
  __shared__ float u[2][260];
  u[0][d] = in[r0 * DD + d];
  u[1][d] = in[(r0 + 1) * DD + d];
  __syncthreads();
  float a0 = 0.f, a1 = 0.f;
  const float4* w4 = (const float4*)(W + d * DD);
  const float4* u0 = (const float4*)&u[0][0];
  const float4* u1 = (const float4*)&u[1][0];
#pragma unroll 8
  for (int k4 = 0; k4 < 64; k4++) {
    float4 w = w4[k4], x0 = u0[k4], x1 = u1[k4];
    a0 += x0.x*w.x + x0.y*w.y + x0.z*w.z + x0.w*w.w;
    a1 += x1.x*w.x + x1.y*w.y + x1.z*w.z + x1.w*w.w;
  }
  float b = bias[d];
  out[r0 * DD + d]       = (a0 + b) * scale;
  out[(r0 + 1) * DD + d] = (a1 + b) * scale;
}

// --- zero the 64 rowgroup counters (each graph replay) -------------------
__global__ void k_zero_cnt(int* __restrict__ c) { c[threadIdx.x] = 0; }

// --- persistent cooperative scan: all 64 steps in one kernel -------------
// 512 blocks (2/CU), 256 thr. Block = 8 rows x 32 cols. W in VGPRs (once).
// Cross-block exchange via RELAXED agent-scope atomics (sc0/sc1 bypassing
// ops at the L3 coherence point) — NO acquire/release cache fences in the
// loop (round-6 lesson: per-spin agent-acquire = L2 invalidate storm,
// 11-64 GB refetch traffic).
__global__ __launch_bounds__(256, 2) void k_scan(float* __restrict__ ws) {
  const int bid = blockIdx.x;
  const int rg = bid & 63, cg = bid >> 6;
  const int b = rg >> 3, rgl = rg & 7, l0 = rgl * 8;
  const int t = threadIdx.x;
  const int cl = t & 7, rs = t >> 3;
  const int c0 = cg * 32 + cl * 4;

  __shared__ float S[10 * 264];     // staged x rows l0-1..l0+8
  __shared__ float PAR[32 * 260];   // split-K partials
  __shared__ float PAR2[4 * 256];
  __shared__ float ZB[256];         // zeu3 tile (step-invariant)

  const float* wct  = ws + WS_WCT;
  const float* zeu3 = ws + WS_ZEU3;
  int* cnt = (int*)(ws + WS_CNT);

  // ---- W into registers: 4 cols x 3 parts x 8 k = 96 floats (static idx)
  float4 wreg[24];
#pragma unroll
  for (int p = 0; p < 3; ++p)
#pragma unroll
    for (int q = 0; q < 2; ++q)
#pragma unroll
      for (int c4 = 0; c4 < 4; ++c4)
        wreg[(p * 2 + q) * 4 + c4] =
            *(const float4*)&wct[(size_t)(c0 + c4) * K3 + p * 256 + rs * 8 + q * 4];

  { // zeu3 tile
    int r = t >> 5, c = t & 31;
    ZB[r * 32 + c] = zeu3[(size_t)(b * 64 + l0 + r) * DD + cg * 32 + c];
  }

  const int cw0 = b * 8 + ((rgl + 7) & 7);
  const int cw1 = b * 8 + rgl;
  const int cw2 = b * 8 + ((rgl + 1) & 7);

  for (int st = 0; st < 64; ++st) {
    const float* xin  = ws + ((st & 1) ? WS_XSA1 : WS_XSA0);
    float*       xout = ws + ((st & 1) ? WS_XSA0 : WS_XSA1);

    if (st > 0) {
      if (t == 0) {   // RELAXED spin: no cache ops per poll
        const int tg = 8 * st;
        while (__hip_atomic_load(&cnt[cw0], __ATOMIC_RELAXED, __HIP_MEMORY_SCOPE_AGENT) < tg)
          __builtin_amdgcn_s_sleep(1);
        while (__hip_atomic_load(&cnt[cw1], __ATOMIC_RELAXED, __HIP_MEMORY_SCOPE_AGENT) < tg)
          __builtin_amdgcn_s_sleep(1);
        while (__hip_atomic_load(&cnt[cw2], __ATOMIC_RELAXED, __HIP_MEMORY_SCOPE_AGENT) < tg)
          __builtin_amdgcn_s_sleep(1);
      }
      __syncthreads();
    }

    // stage 10 rows x 256 f via coherent (bypassing) u64 loads: 1280 u64,
    // 5 per thread, 512B-contiguous per 64-lane wave.
#pragma unroll
    for (int it = 0; it < 5; ++it) {
      int idx = it * 256 + t;
      int j = idx >> 7;               // row 0..9
      int kk = (idx & 127) << 1;      // float offset 0..254
      int l = (l0 + j - 1 + 64) & 63;
      u64 v = __hip_atomic_load(
          (const u64*)(xin + (size_t)(b * 64 + l) * DD + kk),
          __ATOMIC_RELAXED, __HIP_MEMORY_SCOPE_AGENT);
      *(u64*)(&S[j * 264 + kk]) = v;
    }
    __syncthreads();

    float acc[8][4];
#pragma unroll
    for (int r = 0; r < 8; ++r)
#pragma unroll
      for (int c4 = 0; c4 < 4; ++c4) acc[r][c4] = 0.f;

#pragma unroll
    for (int p = 0; p < 3; ++p) {
      const int jof = (p == 0) ? 0 : (p == 1) ? 2 : 1;
#pragma unroll
      for (int r = 0; r < 8; ++r) {
#pragma unroll
        for (int q = 0; q < 2; ++q) {
          float4 x = *(const float4*)&S[(r + jof) * 264 + rs * 8 + q * 4];
#pragma unroll
          for (int c4 = 0; c4 < 4; ++c4) {
            float4 w = wreg[(p * 2 + q) * 4 + c4];
            acc[r][c4] += x.x * w.x + x.y * w.y + x.z * w.z + x.w * w.w;
          }
        }
      }
    }

    // partials -> LDS
#pragma unroll
    for (int r = 0; r < 8; ++r) {
      float4 v4 = {acc[r][0], acc[r][1], acc[r][2], acc[r][3]};
      *(float4*)&PAR[rs * 260 + r * 32 + cl * 4] = v4;
    }
    __syncthreads();

    { // reduce 32 -> 4
      int u = t & 63, v = t >> 6;
      float4 s4 = {0.f, 0.f, 0.f, 0.f};
#pragma unroll
      for (int i = 0; i < 8; ++i) {
        float4 p4 = *(const float4*)&PAR[(v * 8 + i) * 260 + u * 4];
        s4.x += p4.x; s4.y += p4.y; s4.z += p4.z; s4.w += p4.w;
      }
      *(float4*)&PAR2[v * 256 + u * 4] = s4;
    }
    __syncthreads();

    if (t < 64) { // reduce 4 -> 1, add zeu3, coherent store (2 x u64)
      int r = t >> 3, c8 = t & 7;
      float4 s4 = {0.f, 0.f, 0.f, 0.f};
#pragma unroll
      for (int v = 0; v < 4; ++v) {
        float4 p4 = *(const float4*)&PAR2[v * 256 + t * 4];
        s4.x += p4.x; s4.y += p4.y; s4.z += p4.z; s4.w += p4.w;
      }
      float4 zb = *(const float4*)&ZB[r * 32 + c8 * 4];
      s4.x += zb.x; s4.y += zb.y; s4.z += zb.z; s4.w += zb.w;
      size_t off = (size_t)(b * 64 + l0 + r) * DD + cg * 32 + c8 * 4;
      U64F2 lo, hi;
      lo.f[0] = s4.x; lo.f[1] = s4.y;
      hi.f[0] = s4.z; hi.f[1] = s4.w;
      __hip_atomic_store((u64*)(xout + off),     lo.u, __ATOMIC_RELAXED, __HIP_MEMORY_SCOPE_AGENT);
      __hip_atomic_store((u64*)(xout + off + 2), hi.u, __ATOMIC_RELAXED, __HIP_MEMORY_SCOPE_AGENT);
    }

    // __syncthreads drains vmcnt(0): all bypassing stores are globally
    // visible at the coherence point before the counter bump.
    __syncthreads();
    if (t == 0)
      __hip_atomic_fetch_add(&cnt[cw1], 1, __ATOMIC_RELAXED, __HIP_MEMORY_SCOPE_AGENT);
  }
}

// --- fallback single step (used only if cooperative launch fails) --------
__global__ __launch_bounds__(256) void k_step(
    const float* __restrict__ xin, const float* __restrict__ wct,
    const float* __restrict__ zeu3, float* __restrict__ xout) {
  int rg = blockIdx.x, cg = blockIdx.y;
  int b = rg >> 2, l0 = (rg & 3) * 16;
  int t = threadIdx.x, cl = t & 31, rs = t >> 5;
  int c = cg * 32 + cl;
  __shared__ float S[18][260];
  const float* xb = xin + b * LL * DD;
  for (int j = 0; j < 18; ++j) {
    int l = (l0 + j - 1 + LL) & (LL - 1);
    S[j][t] = xb[l * DD + t];
  }
  __syncthreads();
  float a0 = 0.f, a1 = 0.f;
  const float* wb = wct + c * K3;
#pragma unroll
  for (int p = 0; p < 3; ++p) {
    int j0 = rs + ((p == 0) ? 0 : (p == 1) ? 2 : 1);
    const float4* w4 = (const float4*)(wb + p * 256);
    const float4* u0 = (const float4*)&S[j0][0];
    const float4* u1 = (const float4*)&S[j0 + 8][0];
#pragma unroll 8
    for (int k4 = 0; k4 < 64; ++k4) {
      float4 w = w4[k4], x0 = u0[k4], x1 = u1[k4];
      a0 += x0.x*w.x + x0.y*w.y + x0.z*w.z + x0.w*w.w;
      a1 += x1.x*w.x + x1.y*w.y + x1.z*w.z + x1.w*w.w;
    }
  }
  int r0 = b * LL + l0 + rs;
  int r1 = r0 + 8;
  xout[r0 * DD + c] = a0 + zeu3[r0 * DD + c];
  xout[r1 * DD + c] = a1 + zeu3[r1 * DD + c];
}

// --- split embed into bf16 hi/lo (MFMA path only) ------------------------
__global__ __launch_bounds__(256) void k_split_e(
    const float* __restrict__ e, unsigned short* __restrict__ eh,
    unsigned short* __restrict__ el) {
  int i = (blockIdx.x * 256 + threadIdx.x) * 4;
  float4 v = *(const float4*)(e + i);
  float f[4] = {v.x, v.y, v.z, v.w};
  u16x4 h, l;
#pragma unroll
  for (int j = 0; j < 4; ++j) {
    unsigned short hb = f2bf(f[j]);
    h[j] = hb;
    l[j] = f2bf(f[j] - bf2f(hb));
  }
  *(u16x4*)(eh + i) = h;
  *(u16x4*)(el + i) = l;
}

// --- split U = [emit ; ze] into bf16 hi/lo (MFMA path only) --------------
__global__ __launch_bounds__(256) void k_split_u(float* __restrict__ ws) {
  int row = blockIdx.x, d = threadIdx.x;
  float v = (row < RR) ? ws[WS_EMIT + row * DD + d]
                       : ws[WS_ZE + (row - RR) * DD + d];
  unsigned short hb = f2bf(v);
  unsigned short lb = f2bf(v - bf2f(hb));
  ((unsigned short*)(ws + WS_UHI))[row * DD + d] = hb;
  ((unsigned short*)(ws + WS_ULO))[row * DD + d] = lb;
}

// --- head GEMM via MFMA, split-precision bf16, fused online LSE ----------
// grid (32 rowgroups of 32, 32 vchunks of 128), 256 thr = 4 waves.
__global__ __launch_bounds__(256) void k_head_mfma(
    const unsigned short* __restrict__ uh, const unsigned short* __restrict__ ul,
    const unsigned short* __restrict__ eh, const unsigned short* __restrict__ el,
    float* __restrict__ hpart) {
  int row0 = blockIdx.x * 32;
  int v0 = blockIdx.y * 128;
  int t = threadIdx.x, lane = t & 63, w = t >> 6;
  int wr = w >> 1, wc = w & 1;
  __shared__ unsigned short UH[32 * 264];
  __shared__ unsigned short UL[32 * 264];
#pragma unroll
  for (int it = 0; it < 4; ++it) {
    int r = it * 8 + (t >> 5);
    int c8 = (t & 31) * 8;
    *(u16x8*)(&UH[r * 264 + c8]) = *(const u16x8*)(uh + (row0 + r) * DD + c8);
    *(u16x8*)(&UL[r * 264 + c8]) = *(const u16x8*)(ul + (row0 + r) * DD + c8);
  }
  __syncthreads();

  f32x4 acc[4];
#pragma unroll
  for (int q = 0; q < 4; ++q) acc[q] = (f32x4){0.f, 0.f, 0.f, 0.f};

  int arow = wr * 16 + (lane & 15);
  int kof = 8 * (lane >> 4);
  const unsigned short* Ah = &UH[arow * 264 + kof];
  const unsigned short* Al = &UL[arow * 264 + kof];
  int vbase = v0 + wc * 64 + (lane & 15);

#pragma unroll
  for (int p = 0; p < 3; ++p) {
    const unsigned short* Ab = (p == 2) ? Al : Ah;
    const unsigned short* Ebl = ((p == 1) ? el : eh) + (size_t)vbase * DD + kof;
#pragma unroll
    for (int ks = 0; ks < 8; ++ks) {
      int k0 = ks * 32;
      bf16x8 a = *(const bf16x8*)(Ab + k0);
#pragma unroll
      for (int vt = 0; vt < 4; ++vt) {
        bf16x8 bfr = *(const bf16x8*)(Ebl + vt * 16 * DD + k0);
        acc[vt] = __builtin_amdgcn_mfma_f32_16x16x32_bf16(a, bfr, acc[vt], 0, 0, 0);
      }
    }
  }

  int chunk = blockIdx.y * 2 + wc;   // 0..63
#pragma unroll
  for (int i = 0; i < 4; ++i) {
    float mm = -1e30f;
#pragma unroll
    for (int vt = 0; vt < 4; ++vt) mm = fmaxf(mm, acc[vt][i]);
#pragma unroll
    for (int o = 1; o < 16; o <<= 1) mm = fmaxf(mm, __shfl_xor(mm, o, 64));
    float ss = 0.f;
#pragma unroll
    for (int vt = 0; vt < 4; ++vt) ss += __expf(acc[vt][i] - mm);
#pragma unroll
    for (int o = 1; o < 16; o <<= 1) ss += __shfl_xor(ss, o, 64);
    if ((lane & 15) == 0) {
      int row = row0 + wr * 16 + (lane >> 4) * 4 + i;
      hpart[(row * 64 + chunk) * 2]     = mm;
      hpart[(row * 64 + chunk) * 2 + 1] = ss;
    }
  }
}

// --- fallback f32 head: grid (64 rowgroups of 16, 32 vchunks of 128) -----
__global__ __launch_bounds__(256) void k_head_f32(
    const float* __restrict__ embed, float* __restrict__ ws) {
  int rg = blockIdx.x, vc = blockIdx.y;
  int t = threadIdx.x, vl = t & 63, rs = t >> 6;
  __shared__ float U[16][260];
  int row0 = rg * 16;
  const float* src = (row0 < RR) ? (ws + WS_EMIT + row0 * DD)
                                 : (ws + WS_ZE + (row0 - RR) * DD);
  for (int j = 0; j < 16; j++) U[j][t] = src[j * DD + t];
  __syncthreads();
  float m[4], s[4];
#pragma unroll
  for (int q = 0; q < 4; q++) { m[q] = -1e30f; s[q] = 0.f; }
  for (int it = 0; it < 2; it++) {
    int v = vc * 128 + it * 64 + vl;
    const float4* e4 = (const float4*)(embed + (size_t)v * DD);
    float acc[4] = {0.f, 0.f, 0.f, 0.f};
#pragma unroll 4
    for (int k4 = 0; k4 < 64; k4++) {
      float4 e = e4[k4];
#pragma unroll
      for (int q = 0; q < 4; q++) {
        float4 u = ((const float4*)&U[rs + q*4][0])[k4];
        acc[q] += u.x*e.x + u.y*e.y + u.z*e.z + u.w*e.w;
      }
    }
#pragma unroll
    for (int q = 0; q < 4; q++) {
      float mn = fmaxf(m[q], acc[q]);
      s[q] = s[q] * __expf(m[q] - mn) + __expf(acc[q] - mn);
      m[q] = mn;
    }
  }
#pragma unroll
  for (int o = 32; o > 0; o >>= 1) {
#pragma unroll
    for (int q = 0; q < 4; q++) {
      float mo = __shfl_xor(m[q], o, 64), so = __shfl_xor(s[q], o, 64);
      float mn = fmaxf(m[q], mo);
      s[q] = s[q] * __expf(m[q] - mn) + so * __expf(mo - mn);
      m[q] = mn;
    }
  }
  if (vl == 0) {
#pragma unroll
    for (int q = 0; q < 4; q++) {
      int row = row0 + rs + q*4;
      ws[WS_HPART + (row*32 + vc)*2]     = m[q];
      ws[WS_HPART + (row*32 + vc)*2 + 1] = s[q];
    }
  }
}

// --- ylog[v] = yvec · embed[v] -------------------------------------------
__global__ __launch_bounds__(256) void k_ylog(
    const float* __restrict__ embed, float* __restrict__ ws) {
  __shared__ float y[DD];
  int t = threadIdx.x;
  y[t] = ws[WS_YVEC + t];
  __syncthreads();
  int w = t >> 6, lane = t & 63;
  for (int i = 0; i < 16; i++) {
    int v = blockIdx.x * 64 + i * 4 + w;
    float p = 0.f;
#pragma unroll
    for (int j = 0; j < 4; j++) p += y[lane + 64*j] * embed[v * DD + lane + 64*j];
    p = waveSum(p);
    if (lane == 0) ws[WS_YLOG + v] = p;
  }
}

// --- ylse = logsumexp(ylog) ----------------------------------------------
__global__ __launch_bounds__(256) void k_ylse(float* __restrict__ ws) {
  int t = threadIdx.x;
  float m = -1e30f, s = 0.f;
  for (int v = t; v < VV; v += 256) {
    float lg = ws[WS_YLOG + v];
    float mn = fmaxf(m, lg);
    s = s * __expf(m - mn) + __expf(lg - mn);
    m = mn;
  }
#pragma unroll
  for (int o = 32; o > 0; o >>= 1) {
    float mo = __shfl_xor(m, o, 64), so = __shfl_xor(s, o, 64);
    float mn = fmaxf(m, mo);
    s = s * __expf(m - mn) + so * __expf(mo - mn);
    m = mn;
  }
  __shared__ float rm[4], rv[4];
  int lane = t & 63, w = t >> 6;
  if (lane == 0) { rm[w] = m; rv[w] = s; }
  __syncthreads();
  if (t == 0) {
    float M = fmaxf(fmaxf(rm[0], rm[1]), fmaxf(rm[2], rm[3]));
    float S = rv[0]*__expf(rm[0]-M) + rv[1]*__expf(rm[1]-M) +
              rv[2]*__expf(rm[2]-M) + rv[3]*__expf(rm[3]-M);
    ws[WS_YLSE] = M + logf(S);
  }
}

// --- sel logits: s0,s1,s2 per row ----------------------------------------
__global__ __launch_bounds__(256) void k_sel(
    const float* __restrict__ xks, float* __restrict__ ws) {
  int row = blockIdx.x * 4 + (threadIdx.x >> 6);
  int lane = threadIdx.x & 63;
  const float* xr = ws + WS_XSA0 + row * DD;
  float a0 = 0.f, a1 = 0.f, a2 = 0.f;
#pragma unroll
  for (int j = 0; j < 4; j++) {
    float xv = xr[lane + 64*j];
    a0 += xv * xks[lane + 64*j];
    a1 += xv * xks[DD + lane + 64*j];
    a2 += xv * ws[WS_YK + lane + 64*j];
  }
  a0 = waveSum(a0); a1 = waveSum(a1); a2 = waveSum(a2);
  if (lane == 0) {
    ws[WS_SEL + row*4 + 0] = a0;
    ws[WS_SEL + row*4 + 1] = a1;
    ws[WS_SEL + row*4 + 2] = a2;
  }
}

// --- target logits: dot(cand_row, embed[x]) ------------------------------
__global__ __launch_bounds__(256) void k_tgt(
    const int* __restrict__ x, const float* __restrict__ embed,
    float* __restrict__ ws) {
  int row = blockIdx.x * 4 + (threadIdx.x >> 6);
  int lane = threadIdx.x & 63;
  int r5 = row & (RR - 1);
  const float* vec = (row < RR) ? (ws + WS_EMIT + r5 * DD) : (ws + WS_ZE + r5 * DD);
  int v = x[r5];
  float p = 0.f;
#pragma unroll
  for (int j = 0; j < 4; j++) p += vec[lane + 64*j] * embed[v * DD + lane + 64*j];
  p = waveSum(p);
  if (lane == 0) ws[WS_TGT + row] = p;
}

// --- combine nch per-chunk partials into per-row LSE ---------------------
__global__ __launch_bounds__(256) void k_comb(float* __restrict__ ws, int nch) {
  int row = blockIdx.x * 256 + threadIdx.x;
  const float* hp = ws + WS_HPART + row * nch * 2;
  float M = -1e30f;
  for (int c = 0; c < nch; c++) M = fmaxf(M, hp[c * 2]);
  float S = 0.f;
  for (int c = 0; c < nch; c++) S += hp[c * 2 + 1] * __expf(hp[c * 2] - M);
  ws[WS_LSE + row] = M + logf(S);
}

// --- final: mixture prob at target, sqrt, mean over L, negate ------------
__global__ __launch_bounds__(64) void k_final(
    const int* __restrict__ x, float* __restrict__ ws, float* __restrict__ out) {
  int b = blockIdx.x, l = threadIdx.x, r = b * 64 + l;
  float s0 = ws[WS_SEL + r*4], s1 = ws[WS_SEL + r*4+1], s2 = ws[WS_SEL + r*4+2];
  float mx = fmaxf(s0, fmaxf(s1, s2));
  float den = expf(s0 - mx) + expf(s1 - mx) + 64.f * expf(s2 - mx);
  float lsel = mx + logf(den);
  int xv = x[r];
  float P0 = expf(s0 - lsel + ws[WS_TGT + r]      - ws[WS_LSE + r]);
  float P1 = expf(s1 - lsel + ws[WS_TGT + RR + r] - ws[WS_LSE + RR + r]);
  float Py = expf(s2 - lsel + ws[WS_YLOG + xv]    - ws[WS_YLSE]);
  float cent = sqrtf(P0 + P1 + 64.f * Py);
  float sum = waveSum(cent);
  if (l == 0) out[b] = -(sum * (1.0f / 64.f));
}

extern "C" void kernel_launch(void* const* d_in, const int* in_sizes, int n_in,
                              void* d_out, int out_size, void* d_ws, size_t ws_size,
                              hipStream_t stream) {
  (void)in_sizes; (void)n_in; (void)out_size;
  const int*   x     = (const int*)d_in[0];
  const int*   z     = (const int*)d_in[1];
  const float* embed = (const float*)d_in[2];
  const float* initw = (const float*)d_in[3];
  const float* tw    = (const float*)d_in[4];
  const float* tb    = (const float*)d_in[5];
  const float* cw    = (const float*)d_in[6];
  const float* uw    = (const float*)d_in[7];
  const float* xks   = (const float*)d_in[8];
  const float* xkdw  = (const float*)d_in[9];
  const float* xkdb  = (const float*)d_in[10];
  const float* emiw  = (const float*)d_in[11];
  const float* emib  = (const float*)d_in[12];
  float* ws  = (float*)d_ws;
  float* out = (float*)d_out;

  const bool use_mfma = ws_size >= (size_t)WS_TOTAL_MFMA * sizeof(float);

  hipLaunchKernelGGL(k_norm_rows, dim3(RR + 2), dim3(256), 0, stream, z, embed, initw, ws);
  hipLaunchKernelGGL(k_build_w,   dim3(256),    dim3(256), 0, stream, tw, cw, ws + WS_WCT);
  hipLaunchKernelGGL(k_yk,        dim3(1),      dim3(256), 0, stream, xkdw, xkdb, ws);
  hipLaunchKernelGGL(k_bcast,     dim3(512),    dim3(256), 0, stream, ws);
  hipLaunchKernelGGL(k_rowmat2,   dim3(256),    dim3(256), 0, stream,
                     ws + WS_ZE, uw, tb, ws + WS_ZEU3, 1.0f / 3.0f);
  if (use_mfma) {
    hipLaunchKernelGGL(k_split_e, dim3(1024),   dim3(256), 0, stream, embed,
                       (unsigned short*)(ws + WS_EHI), (unsigned short*)(ws + WS_ELO));
  }
  hipLaunchKernelGGL(k_ylog,      dim3(64),     dim3(256), 0, stream, embed, ws);
  hipLaunchKernelGGL(k_ylse,      dim3(1),      dim3(256), 0, stream, ws);

  // ---- scan: persistent cooperative kernel (fallback: 64 step launches) --
  hipLaunchKernelGGL(k_zero_cnt, dim3(1), dim3(64), 0, stream, (int*)(ws + WS_CNT));
  {
    float* wsp = ws;
    void* kargs[] = {&wsp};
    hipError_t err = hipLaunchCooperativeKernel(
        reinterpret_cast<void*>(k_scan), dim3(512), dim3(256), kargs, 0, stream);
    if (err != hipSuccess) {
      for (int t = 0; t < 64; t++) {
        const float* xin = ws + ((t & 1) ? WS_XSA1 : WS_XSA0);
        float*       xo  = ws + ((t & 1) ? WS_XSA0 : WS_XSA1);
        hipLaunchKernelGGL(k_step, dim3(32, 8), dim3(256), 0, stream,
                           xin, ws + WS_WCT, ws + WS_ZEU3, xo);
      }
    }
  }

  hipLaunchKernelGGL(k_rowmat2, dim3(256), dim3(256), 0, stream,
                     ws + WS_XSA0, emiw, emib, ws + WS_EMIT, 1.0f);
  hipLaunchKernelGGL(k_sel,     dim3(128), dim3(256), 0, stream, xks, ws);
  hipLaunchKernelGGL(k_tgt,     dim3(256), dim3(256), 0, stream, x, embed, ws);
  if (use_mfma) {
    hipLaunchKernelGGL(k_split_u,   dim3(1024),   dim3(256), 0, stream, ws);
    hipLaunchKernelGGL(k_head_mfma, dim3(32, 32), dim3(256), 0, stream,
                       (const unsigned short*)(ws + WS_UHI),
                       (const unsigned short*)(ws + WS_ULO),
                       (const unsigned short*)(ws + WS_EHI),
                       (const unsigned short*)(ws + WS_ELO),
                       ws + WS_HPART);
    hipLaunchKernelGGL(k_comb,  dim3(4), dim3(256), 0, stream, ws, 64);
  } else {
    hipLaunchKernelGGL(k_head_f32, dim3(64, 32), dim3(256), 0, stream, embed, ws);
    hipLaunchKernelGGL(k_comb,  dim3(4), dim3(256), 0, stream, ws, 32);
  }
  hipLaunchKernelGGL(k_final, dim3(8), dim3(64),  0, stream, x, ws, out);
}